// Round 4
// baseline (209.207 us; speedup 1.0000x reference)
//
#include <hip/hip_runtime.h>

#define HH 64
#define WW 64
#define S  68          // padded LDS row stride (floats)
#define PH 66          // padded rows (1-px zero frame)
#define NLQ 10
#define NR 8           // rows per thread (512 threads = 8 waves = 2/SIMD)

// One block per image (grid=256 = 1 block/CU). Thread t: column x=t&63, rows
// y0..y0+7.
//
// History:
//  R2-R7: ~110us, VGPR=108. Wt[90]+q0r[80] loaded from LDS -> demoted to
//         AGPRs; Wt read 8x/step -> ~720 v_accvgpr_read/step = 2x VALU.
//  R8: LDS occupancy-pad was DSE'd - no-op.
//  R9: asm "a"-pinning of q0r -> array went to SCRATCH (814MB fetch, 940us).
//  R10: Wt re-read from LDS per channel: removed the accvgpr reads but moved
//       the cost to the per-CU LDS pipe (8 waves x 30 ds_read_b128 x ~12cy
//       = 2880cy/step > VALU 3600cy/4SIMD) -> 122us, VALUBusy 91%.
//  R11 (this): weights go to SGPRs. wtr/Wq are wave-uniform global data with
//       compile-time indices -> uniformity analysis emits s_load into SGPRs
//       (LDS staging was what forced them into V/AGPRs all along: LDS has no
//       scalar path). v_fma_f32 takes one SGPR operand -> weights cost zero
//       VALU and zero LDS ops in the K-loop. q0r stays a plain local array
//       (implicit AGPR demotion = 80 cheap accvgpr reads/step, its only use).
__global__ __launch_bounds__(512)
__attribute__((amdgpu_waves_per_eu(2, 2)))
void vin_fused(
    const float* __restrict__ X,    // [B,2,64,64]
    const float* __restrict__ Wh,   // [150,2,3,3]
    const float* __restrict__ bh,   // [150]
    const float* __restrict__ Wr,   // [150]
    const float* __restrict__ Wq,   // [10,1,3,3]
    const float* __restrict__ wtr,  // [10,1,3,3] transition
    const float* __restrict__ Wc,   // [4096]
    const float* __restrict__ bc,   // [1]
    float* __restrict__ out)        // [256 critic] ++ [256*40960 q]
{
  __shared__ float vb[2][PH * S];
  __shared__ float rb[PH * S];
  __shared__ float Wef[19];
  __shared__ float Wpart[152];
  __shared__ float red[8];

  const int b  = blockIdx.x;
  const int t  = threadIdx.x;
  const int x  = t & 63;
  const int yg = t >> 6;
  const int y0 = yg * NR;
  const int base0 = y0 * S + x;   // top-left of 3x3 window for row y0 (padded)

  // ---- zero LDS (frames must be 0; interiors overwritten) ----
  {
    float* vbf = &vb[0][0];
    for (int i = t; i < 2 * PH * S; i += 512) vbf[i] = 0.f;
    for (int i = t; i < PH * S; i += 512) rb[i] = 0.f;
  }
  __syncthreads();

  // ---- stage X into vb interiors; collapse 150-ch conv to Wef[19] ----
  const float* Xb = X + (size_t)b * (2 * HH * WW);
  for (int i = t; i < HH * WW; i += 512) {
    const int yy = i >> 6, xx = i & 63;
    vb[0][(yy + 1) * S + xx + 1] = Xb[i];
    vb[1][(yy + 1) * S + xx + 1] = Xb[HH * WW + i];
  }
  if (t < 152) {                       // parallel collapse: 19 outputs x 8 parts
    const int i = t >> 3, part = t & 7;
    float s = 0.f;
    if (i < 18) {
      for (int c = part; c < 150; c += 8) s += Wr[c] * Wh[c * 18 + i];
    } else {
      for (int c = part; c < 150; c += 8) s += Wr[c] * bh[c];
    }
    Wpart[t] = s;
  }
  __syncthreads();
  if (t < 19) {
    float s = 0.f;
#pragma unroll
    for (int k = 0; k < 8; ++k) s += Wpart[t * 8 + k];
    Wef[t] = s;
  }
  __syncthreads();

  // ---- r = conv(X, Weff, pad=1) + beff -> rb ----
  {
    float We[19];
#pragma unroll
    for (int i = 0; i < 19; ++i) We[i] = Wef[i];
#pragma unroll
    for (int j = 0; j < NR; ++j) {
      const int tb = base0 + j * S;
      float s = We[18];
#pragma unroll
      for (int dy = 0; dy < 3; ++dy)
#pragma unroll
        for (int dx = 0; dx < 3; ++dx) {
          const int idx = tb + dy * S + dx;
          s = fmaf(vb[0][idx], We[dy * 3 + dx], s);
          s = fmaf(vb[1][idx], We[9 + dy * 3 + dx], s);
        }
      rb[tb + S + 1] = s;
    }
  }
  __syncthreads();

  // ---- q0 = conv(r, Wq, pad=1) -> q0r regs; v_init = max_l q0 -> vb[0] ----
  // Wq read directly from global: uniform + constant index -> s_load -> SGPR.
  float q0r[NR][NLQ];
  {
    float m[NR];
#pragma unroll
    for (int l = 0; l < NLQ; ++l) {
      const float w0 = Wq[l * 9 + 0], w1 = Wq[l * 9 + 1], w2 = Wq[l * 9 + 2];
      const float w3 = Wq[l * 9 + 3], w4 = Wq[l * 9 + 4], w5 = Wq[l * 9 + 5];
      const float w6 = Wq[l * 9 + 6], w7 = Wq[l * 9 + 7], w8 = Wq[l * 9 + 8];
#pragma unroll
      for (int j = 0; j < NR; ++j) {
        const int a = base0 + j * S;
        float s;
        s = fmaf(w0, rb[a],             0.f);
        s = fmaf(w1, rb[a + 1],         s);
        s = fmaf(w2, rb[a + 2],         s);
        s = fmaf(w3, rb[a + S],         s);
        s = fmaf(w4, rb[a + S + 1],     s);
        s = fmaf(w5, rb[a + S + 2],     s);
        s = fmaf(w6, rb[a + 2 * S],     s);
        s = fmaf(w7, rb[a + 2 * S + 1], s);
        s = fmaf(w8, rb[a + 2 * S + 2], s);
        q0r[j][l] = s;
        m[j] = (l == 0) ? s : fmaxf(m[j], s);
      }
    }
#pragma unroll
    for (int j = 0; j < NR; ++j) vb[0][base0 + (j + 1) * S + 1] = m[j];
  }
  __syncthreads();

  // ---- K-loop: q = q0 + conv(v, w); v = max_ch(q) ----
  // Weights from global wtr via scalar loads (SGPRs): zero VALU/LDS cost.
  // Window rows in 30 VGPRs from LDS (stride-1 -> 2 lanes/bank -> free).
  auto step = [&](const float* __restrict__ vin, float* __restrict__ vout) {
    float win[NR + 2][3];
#pragma unroll
    for (int rr = 0; rr < NR + 2; ++rr) {
      const int a = base0 + rr * S;
      win[rr][0] = vin[a];
      win[rr][1] = vin[a + 1];
      win[rr][2] = vin[a + 2];
    }
    float m[NR];
#pragma unroll
    for (int l = 0; l < NLQ; ++l) {
      const float wt0 = wtr[l * 9 + 0], wt1 = wtr[l * 9 + 1], wt2 = wtr[l * 9 + 2];
      const float wt3 = wtr[l * 9 + 3], wt4 = wtr[l * 9 + 4], wt5 = wtr[l * 9 + 5];
      const float wt6 = wtr[l * 9 + 6], wt7 = wtr[l * 9 + 7], wt8 = wtr[l * 9 + 8];
#pragma unroll
      for (int j = 0; j < NR; ++j) {
        float s = q0r[j][l];
        s = fmaf(wt0, win[j][0],     s);
        s = fmaf(wt1, win[j][1],     s);
        s = fmaf(wt2, win[j][2],     s);
        s = fmaf(wt3, win[j + 1][0], s);
        s = fmaf(wt4, win[j + 1][1], s);
        s = fmaf(wt5, win[j + 1][2], s);
        s = fmaf(wt6, win[j + 2][0], s);
        s = fmaf(wt7, win[j + 2][1], s);
        s = fmaf(wt8, win[j + 2][2], s);
        m[j] = (l == 0) ? s : fmaxf(m[j], s);
      }
    }
#pragma unroll
    for (int j = 0; j < NR; ++j) vout[base0 + (j + 1) * S + 1] = m[j];
    __syncthreads();
  };

#pragma unroll 1
  for (int s2 = 0; s2 < 19; ++s2) { step(vb[0], vb[1]); step(vb[1], vb[0]); }
  step(vb[0], vb[1]);   // it = 38: reads vb[0], writes vb[1]

  // ---- final iteration (it=39): emit q + critic dot ----
  float wcv[NR];
#pragma unroll
  for (int j = 0; j < NR; ++j) wcv[j] = Wc[(y0 + j) * WW + x];

  float* qo = out + 256 + (size_t)b * (NLQ * HH * WW) + y0 * WW + x;
  float acc = 0.f;
  {
    const float* vin = vb[1];
    float win[NR + 2][3];
#pragma unroll
    for (int rr = 0; rr < NR + 2; ++rr) {
      const int a = base0 + rr * S;
      win[rr][0] = vin[a];
      win[rr][1] = vin[a + 1];
      win[rr][2] = vin[a + 2];
    }
    float m[NR];
#pragma unroll
    for (int l = 0; l < NLQ; ++l) {
      const float wt0 = wtr[l * 9 + 0], wt1 = wtr[l * 9 + 1], wt2 = wtr[l * 9 + 2];
      const float wt3 = wtr[l * 9 + 3], wt4 = wtr[l * 9 + 4], wt5 = wtr[l * 9 + 5];
      const float wt6 = wtr[l * 9 + 6], wt7 = wtr[l * 9 + 7], wt8 = wtr[l * 9 + 8];
#pragma unroll
      for (int j = 0; j < NR; ++j) {
        float s = q0r[j][l];
        s = fmaf(wt0, win[j][0],     s);
        s = fmaf(wt1, win[j][1],     s);
        s = fmaf(wt2, win[j][2],     s);
        s = fmaf(wt3, win[j + 1][0], s);
        s = fmaf(wt4, win[j + 1][1], s);
        s = fmaf(wt5, win[j + 1][2], s);
        s = fmaf(wt6, win[j + 2][0], s);
        s = fmaf(wt7, win[j + 2][1], s);
        s = fmaf(wt8, win[j + 2][2], s);
        qo[l * (HH * WW) + j * WW] = s;
        m[j] = (l == 0) ? s : fmaxf(m[j], s);
      }
    }
#pragma unroll
    for (int j = 0; j < NR; ++j) acc = fmaf(m[j], wcv[j], acc);
  }

  // ---- block-reduce critic ----
#pragma unroll
  for (int off = 32; off > 0; off >>= 1) acc += __shfl_down(acc, off);
  if (x == 0) red[yg] = acc;
  __syncthreads();
  if (t == 0) {
    float s = bc[0];
#pragma unroll
    for (int i = 0; i < 8; ++i) s += red[i];
    out[b] = s;
  }
}

extern "C" void kernel_launch(void* const* d_in, const int* in_sizes, int n_in,
                              void* d_out, int out_size, void* d_ws, size_t ws_size,
                              hipStream_t stream) {
  (void)n_in; (void)out_size; (void)d_ws; (void)ws_size;
  const float* X   = (const float*)d_in[0];
  const float* Wh  = (const float*)d_in[1];
  const float* bh  = (const float*)d_in[2];
  const float* Wr  = (const float*)d_in[3];
  const float* Wq  = (const float*)d_in[4];
  const float* wtr = (const float*)d_in[5];
  const float* Wc  = (const float*)d_in[6];
  const float* bc  = (const float*)d_in[7];
  float* out = (float*)d_out;

  const int B = in_sizes[0] / (2 * HH * WW);   // 256
  vin_fused<<<B, 512, 0, stream>>>(X, Wh, bh, Wr, Wq, wtr, Wc, bc, out);
}

// Round 5
// 164.275 us; speedup vs baseline: 1.2735x; 1.2735x over previous
//
#include <hip/hip_runtime.h>

#define HH 64
#define WW 64
#define S  68          // padded LDS row stride (floats)
#define PH 66          // padded rows (1-px zero frame)
#define NLQ 10
#define NP  5          // channel pairs
#define NR 8           // rows per thread (512 threads = 8 waves = 2/SIMD)

typedef float f32x2 __attribute__((ext_vector_type(2)));

// One block per image (grid=256 = 1 block/CU). Thread t: column x=t&63, rows
// y0..y0+7.
//
// History:
//  R1 (110us): Wt[90]+q0r[80] from LDS -> AGPR demotion; Wt read 8x/step ->
//      ~720 v_accvgpr_read/step = 2x VALU stream. VALUBusy 104%.
//  R8: LDS occupancy-pad DSE'd - no-op.
//  R9: asm "a"-pinning of q0r -> SCRATCH (814MB fetch, 940us). Never do that.
//  R10 (122us): Wt re-read from LDS per step -> LDS pipe binds (VALUBusy 91%).
//  R11 (148us): Wt re-read from global per step -> loads can't hoist across
//      the K-loop __syncthreads (barrier = full clobber); lgkmcnt serialization
//      (VALUBusy 75%). LESSON: weight residency must be SSA values loaded
//      BEFORE the loop - registers are the only thing barriers can't touch.
//  R12 (this): V_PK_FMA_F32. Channel-paired (l=2p,2p+1) K-loop:
//      720 fma -> 360 pk_fma, 72 max -> ~48 pk/scalar max. Weight pairs built
//      pre-loop from uniform loads (SGPR pairs = VOP3P's scalar operand);
//      window splat via op_sel; q0 pairs plain locals (AGPR demotion = 80
//      cheap reads/step). Same per-channel fma order -> bitwise identical.
__global__ __launch_bounds__(512)
__attribute__((amdgpu_waves_per_eu(2, 2)))
void vin_fused(
    const float* __restrict__ X,    // [B,2,64,64]
    const float* __restrict__ Wh,   // [150,2,3,3]
    const float* __restrict__ bh,   // [150]
    const float* __restrict__ Wr,   // [150]
    const float* __restrict__ Wq,   // [10,1,3,3]
    const float* __restrict__ wtr,  // [10,1,3,3] transition
    const float* __restrict__ Wc,   // [4096]
    const float* __restrict__ bc,   // [1]
    float* __restrict__ out)        // [256 critic] ++ [256*40960 q]
{
  __shared__ float vb[2][PH * S];
  __shared__ float rb[PH * S];
  __shared__ float Wef[19];
  __shared__ float Wpart[152];
  __shared__ float red[8];

  const int b  = blockIdx.x;
  const int t  = threadIdx.x;
  const int x  = t & 63;
  const int yg = t >> 6;
  const int y0 = yg * NR;
  const int base0 = y0 * S + x;   // top-left of 3x3 window for row y0 (padded)

  // ---- zero LDS (frames must be 0; interiors overwritten) ----
  {
    float* vbf = &vb[0][0];
    for (int i = t; i < 2 * PH * S; i += 512) vbf[i] = 0.f;
    for (int i = t; i < PH * S; i += 512) rb[i] = 0.f;
  }
  __syncthreads();

  // ---- stage X into vb interiors; collapse 150-ch conv to Wef[19] ----
  const float* Xb = X + (size_t)b * (2 * HH * WW);
  for (int i = t; i < HH * WW; i += 512) {
    const int yy = i >> 6, xx = i & 63;
    vb[0][(yy + 1) * S + xx + 1] = Xb[i];
    vb[1][(yy + 1) * S + xx + 1] = Xb[HH * WW + i];
  }
  if (t < 152) {                       // parallel collapse: 19 outputs x 8 parts
    const int i = t >> 3, part = t & 7;
    float s = 0.f;
    if (i < 18) {
      for (int c = part; c < 150; c += 8) s += Wr[c] * Wh[c * 18 + i];
    } else {
      for (int c = part; c < 150; c += 8) s += Wr[c] * bh[c];
    }
    Wpart[t] = s;
  }
  __syncthreads();
  if (t < 19) {
    float s = 0.f;
#pragma unroll
    for (int k = 0; k < 8; ++k) s += Wpart[t * 8 + k];
    Wef[t] = s;
  }
  __syncthreads();

  // ---- r = conv(X, Weff, pad=1) + beff -> rb ----
  {
    float We[19];
#pragma unroll
    for (int i = 0; i < 19; ++i) We[i] = Wef[i];
#pragma unroll
    for (int j = 0; j < NR; ++j) {
      const int tb = base0 + j * S;
      float s = We[18];
#pragma unroll
      for (int dy = 0; dy < 3; ++dy)
#pragma unroll
        for (int dx = 0; dx < 3; ++dx) {
          const int idx = tb + dy * S + dx;
          s = fmaf(vb[0][idx], We[dy * 3 + dx], s);
          s = fmaf(vb[1][idx], We[9 + dy * 3 + dx], s);
        }
      rb[tb + S + 1] = s;
    }
  }
  __syncthreads();

  // ---- weight pairs, loaded ONCE into SSA values (uniform -> SGPR pairs).
  // Loaded before any use so nothing forces a per-step reload.
  f32x2 wqp[NP][9];   // q0-conv weights, channel-paired
  f32x2 wtp[NP][9];   // transition weights, channel-paired
#pragma unroll
  for (int p = 0; p < NP; ++p)
#pragma unroll
    for (int k = 0; k < 9; ++k) {
      wqp[p][k] = (f32x2){ Wq[(2 * p) * 9 + k],  Wq[(2 * p + 1) * 9 + k]  };
      wtp[p][k] = (f32x2){ wtr[(2 * p) * 9 + k], wtr[(2 * p + 1) * 9 + k] };
    }

  // ---- q0 = conv(r, Wq, pad=1) -> q0p pairs; v_init = max_l q0 -> vb[0] ----
  f32x2 q0p[NR][NP];
  {
#pragma unroll
    for (int j = 0; j < NR; ++j) {
      const int a = base0 + j * S;
      f32x2 acc[NP];
#pragma unroll
      for (int p = 0; p < NP; ++p) acc[p] = (f32x2){0.f, 0.f};
#pragma unroll
      for (int dy = 0; dy < 3; ++dy)
#pragma unroll
        for (int dx = 0; dx < 3; ++dx) {
          const int k = dy * 3 + dx;
          const float wv = rb[a + dy * S + dx];
          const f32x2 ws = { wv, wv };
#pragma unroll
          for (int p = 0; p < NP; ++p)
            acc[p] = __builtin_elementwise_fma(wqp[p][k], ws, acc[p]);
        }
#pragma unroll
      for (int p = 0; p < NP; ++p) q0p[j][p] = acc[p];
      f32x2 m01 = __builtin_elementwise_max(acc[0], acc[1]);
      f32x2 m23 = __builtin_elementwise_max(acc[2], acc[3]);
      m01 = __builtin_elementwise_max(m01, m23);
      m01 = __builtin_elementwise_max(m01, acc[4]);
      vb[0][base0 + (j + 1) * S + 1] = fmaxf(m01.x, m01.y);
    }
  }
  __syncthreads();

  // ---- K-loop: q = q0 + conv(v, w); v = max_ch(q) ----
  // 360 pk_fma/step (weights in SGPR pairs, window splat, q0 pairs init).
  auto step = [&](const float* __restrict__ vin, float* __restrict__ vout) {
    float win[NR + 2][3];
#pragma unroll
    for (int rr = 0; rr < NR + 2; ++rr) {
      const int a = base0 + rr * S;
      win[rr][0] = vin[a];
      win[rr][1] = vin[a + 1];
      win[rr][2] = vin[a + 2];
    }
#pragma unroll
    for (int j = 0; j < NR; ++j) {
      f32x2 acc[NP];
#pragma unroll
      for (int p = 0; p < NP; ++p) acc[p] = q0p[j][p];
#pragma unroll
      for (int dy = 0; dy < 3; ++dy)
#pragma unroll
        for (int dx = 0; dx < 3; ++dx) {
          const int k = dy * 3 + dx;
          const float wv = win[j + dy][dx];
          const f32x2 ws = { wv, wv };
#pragma unroll
          for (int p = 0; p < NP; ++p)
            acc[p] = __builtin_elementwise_fma(wtp[p][k], ws, acc[p]);
        }
      f32x2 m01 = __builtin_elementwise_max(acc[0], acc[1]);
      f32x2 m23 = __builtin_elementwise_max(acc[2], acc[3]);
      m01 = __builtin_elementwise_max(m01, m23);
      m01 = __builtin_elementwise_max(m01, acc[4]);
      vout[base0 + (j + 1) * S + 1] = fmaxf(m01.x, m01.y);
    }
    __syncthreads();
  };

#pragma unroll 1
  for (int s2 = 0; s2 < 19; ++s2) { step(vb[0], vb[1]); step(vb[1], vb[0]); }
  step(vb[0], vb[1]);   // it = 38: reads vb[0], writes vb[1]

  // ---- final iteration (it=39): emit q + critic dot ----
  float wcv[NR];
#pragma unroll
  for (int j = 0; j < NR; ++j) wcv[j] = Wc[(y0 + j) * WW + x];

  float* qo = out + 256 + (size_t)b * (NLQ * HH * WW) + y0 * WW + x;
  float acc_c = 0.f;
  {
    const float* vin = vb[1];
    float win[NR + 2][3];
#pragma unroll
    for (int rr = 0; rr < NR + 2; ++rr) {
      const int a = base0 + rr * S;
      win[rr][0] = vin[a];
      win[rr][1] = vin[a + 1];
      win[rr][2] = vin[a + 2];
    }
#pragma unroll
    for (int j = 0; j < NR; ++j) {
      f32x2 acc[NP];
#pragma unroll
      for (int p = 0; p < NP; ++p) acc[p] = q0p[j][p];
#pragma unroll
      for (int dy = 0; dy < 3; ++dy)
#pragma unroll
        for (int dx = 0; dx < 3; ++dx) {
          const int k = dy * 3 + dx;
          const float wv = win[j + dy][dx];
          const f32x2 ws = { wv, wv };
#pragma unroll
          for (int p = 0; p < NP; ++p)
            acc[p] = __builtin_elementwise_fma(wtp[p][k], ws, acc[p]);
        }
#pragma unroll
      for (int p = 0; p < NP; ++p) {
        qo[(2 * p)     * (HH * WW) + j * WW] = acc[p].x;
        qo[(2 * p + 1) * (HH * WW) + j * WW] = acc[p].y;
      }
      f32x2 m01 = __builtin_elementwise_max(acc[0], acc[1]);
      f32x2 m23 = __builtin_elementwise_max(acc[2], acc[3]);
      m01 = __builtin_elementwise_max(m01, m23);
      m01 = __builtin_elementwise_max(m01, acc[4]);
      acc_c = fmaf(fmaxf(m01.x, m01.y), wcv[j], acc_c);
    }
  }

  // ---- block-reduce critic ----
#pragma unroll
  for (int off = 32; off > 0; off >>= 1) acc_c += __shfl_down(acc_c, off);
  if (x == 0) red[yg] = acc_c;
  __syncthreads();
  if (t == 0) {
    float s = bc[0];
#pragma unroll
    for (int i = 0; i < 8; ++i) s += red[i];
    out[b] = s;
  }
}

extern "C" void kernel_launch(void* const* d_in, const int* in_sizes, int n_in,
                              void* d_out, int out_size, void* d_ws, size_t ws_size,
                              hipStream_t stream) {
  (void)n_in; (void)out_size; (void)d_ws; (void)ws_size;
  const float* X   = (const float*)d_in[0];
  const float* Wh  = (const float*)d_in[1];
  const float* bh  = (const float*)d_in[2];
  const float* Wr  = (const float*)d_in[3];
  const float* Wq  = (const float*)d_in[4];
  const float* wtr = (const float*)d_in[5];
  const float* Wc  = (const float*)d_in[6];
  const float* bc  = (const float*)d_in[7];
  float* out = (float*)d_out;

  const int B = in_sizes[0] / (2 * HH * WW);   // 256
  vin_fused<<<B, 512, 0, stream>>>(X, Wh, bh, Wr, Wq, wtr, Wc, bc, out);
}